// Round 11
// baseline (203.933 us; speedup 1.0000x reference)
//
#include <hip/hip_runtime.h>
#include <math.h>

#define N_PTS 16384
#define WID   128
#define NHID  5
#define SPTS  16            // points per set
#define PPB   32            // points per block (2 sets, ping-pong)
#define CH    9
#define COLS  (SPTS*CH)     // 144
#define KPAD  132           // stride 66 dwords == 2 mod 32 -> conflict-free b128 column reads
#define NBLK  (N_PTS/PPB)   // 512  (= 2 blocks/CU exactly, no tail)

typedef __attribute__((ext_vector_type(8))) __bf16 bf16x8;
typedef __attribute__((ext_vector_type(4))) float  f32x4;

__device__ __forceinline__ unsigned short f2bf(float x) {
    unsigned int u = __builtin_bit_cast(unsigned int, x);
    u += 0x7FFFu + ((u >> 16) & 1u);          // RNE (no NaNs in this problem)
    return (unsigned short)(u >> 16);
}
__device__ __forceinline__ float bf2f(unsigned short h) {
    unsigned int u = ((unsigned int)h) << 16;
    return __builtin_bit_cast(float, u);
}
// fallback-path split
__device__ __forceinline__ void split_bf(float x, unsigned short& hi, unsigned short& lo) {
    const unsigned int u = __builtin_bit_cast(unsigned int, x);
    hi = (unsigned short)(u >> 16);
    const float rem = x - __builtin_bit_cast(float, u & 0xFFFF0000u);
    lo = (unsigned short)(__builtin_bit_cast(unsigned int, rem) >> 16);
}
// packed bf16 convert: D[15:0]=bf16(v0), D[31:16]=bf16(v1)  (RNE)
__device__ __forceinline__ unsigned int cvtpk(float v0, float v1) {
    unsigned int r;
    asm("v_cvt_pk_bf16_f32 %0, %1, %2" : "=v"(r) : "v"(v0), "v"(v1));
    return r;
}
// split 4 floats into packed hi pair + packed lo pair (lo = exact residual of RNE hi)
__device__ __forceinline__ void split_pk4(const float v0, const float v1,
                                          const float v2, const float v3,
                                          uint2& ph, uint2& pl) {
    const unsigned int h01 = cvtpk(v0, v1);
    const unsigned int h23 = cvtpk(v2, v3);
    const float f0 = __builtin_bit_cast(float, h01 << 16);
    const float f1 = __builtin_bit_cast(float, h01 & 0xFFFF0000u);
    const float f2 = __builtin_bit_cast(float, h23 << 16);
    const float f3 = __builtin_bit_cast(float, h23 & 0xFFFF0000u);
    ph = make_uint2(h01, h23);
    pl = make_uint2(cvtpk(v0 - f0, v1 - f1), cvtpk(v2 - f2, v3 - f3));
}
// a = tanh(x), g = 1 - a^2 (cancellation-free)
__device__ __forceinline__ void fast_tanh_g(float x, float& a, float& g) {
    x = fminf(fmaxf(x, -40.0f), 40.0f);
    const float e = __builtin_amdgcn_exp2f(2.88539008177793f * x);   // exp(2x)
    const float r = __builtin_amdgcn_rcpf(e + 1.0f);
    a = 1.0f - 2.0f * r;
    g = 4.0f * e * r * r;
}

// ---------------- pack uW_hid into MFMA fragment order (bf16 hi/lo) ----------------
__global__ __launch_bounds__(64) void pack_w(const float* __restrict__ uWhid,
                                             unsigned short* __restrict__ whi,
                                             unsigned short* __restrict__ wlo)
{
    const int f  = blockIdx.x;            // 0..159
    const int v  = threadIdx.x;           // 0..63
    const int l  = f >> 5;
    const int s  = (f >> 3) & 3;
    const int rt = f & 7;
    const int row = rt*16 + (v & 15);
    const int k0  = s*32 + ((v >> 4) << 3);
    const float* src = uWhid + (l*WID + row)*WID + k0;
    unsigned short h[8], lo[8];
#pragma unroll
    for (int j = 0; j < 8; ++j) {
        const float x = src[j];
        h[j]  = f2bf(x);
        lo[j] = f2bf(x - bf2f(h[j]));
    }
    const int off = f*512 + v*8;
    *reinterpret_cast<ushort4*>(&whi[off])   = make_ushort4(h[0],h[1],h[2],h[3]);
    *reinterpret_cast<ushort4*>(&whi[off+4]) = make_ushort4(h[4],h[5],h[6],h[7]);
    *reinterpret_cast<ushort4*>(&wlo[off])   = make_ushort4(lo[0],lo[1],lo[2],lo[3]);
    *reinterpret_cast<ushort4*>(&wlo[off+4]) = make_ushort4(lo[4],lo[5],lo[6],lo[7]);
}

// ---------------- building blocks for the ping-pong kernel ----------------
__device__ __forceinline__ void mfma_layer(
    f32x4 (&acc)[2][CH],
    const unsigned short* __restrict__ whi, const unsigned short* __restrict__ wlo,
    const unsigned short (&act_h)[COLS*KPAD], const unsigned short (&act_l)[COLS*KPAD],
    const float* __restrict__ ubhid, const int l,
    const int lrow0, const int g4, const int rq, const int v,
    const int bcol, const int krow)
{
#pragma unroll
    for (int rt = 0; rt < 2; ++rt) {
        acc[rt][0] = *reinterpret_cast<const f32x4*>(&ubhid[l*WID + lrow0 + rt*16 + g4]);
#pragma unroll
        for (int ct = 1; ct < CH; ++ct) acc[rt][ct] = (f32x4){0.f,0.f,0.f,0.f};
    }
#pragma unroll
    for (int s = 0; s < 4; ++s) {
        bf16x8 bh[CH], bl[CH], ah[2], al[2];
        const int kof = s*32 + krow;
        const int fb  = ((l*4 + s)*8 + rq*2)*512 + v*8;
#pragma unroll
        for (int rt = 0; rt < 2; ++rt) {
            ah[rt] = *reinterpret_cast<const bf16x8*>(&whi[fb + rt*512]);
            al[rt] = *reinterpret_cast<const bf16x8*>(&wlo[fb + rt*512]);
        }
#pragma unroll
        for (int ct = 0; ct < CH; ++ct) {
            const int off = (ct*SPTS + bcol)*KPAD + kof;
            bh[ct] = *reinterpret_cast<const bf16x8*>(&act_h[off]);
            bl[ct] = *reinterpret_cast<const bf16x8*>(&act_l[off]);
        }
#pragma unroll
        for (int rt = 0; rt < 2; ++rt)
#pragma unroll
            for (int ct = 0; ct < CH; ++ct)
                acc[rt][ct] = __builtin_amdgcn_mfma_f32_16x16x32_bf16(ah[rt], bh[ct], acc[rt][ct], 0,0,0);
#pragma unroll
        for (int rt = 0; rt < 2; ++rt)
#pragma unroll
            for (int ct = 0; ct < CH; ++ct)
                acc[rt][ct] = __builtin_amdgcn_mfma_f32_16x16x32_bf16(ah[rt], bl[ct], acc[rt][ct], 0,0,0);
#pragma unroll
        for (int rt = 0; rt < 2; ++rt)
#pragma unroll
            for (int ct = 0; ct < CH; ++ct)
                acc[rt][ct] = __builtin_amdgcn_mfma_f32_16x16x32_bf16(al[rt], bh[ct], acc[rt][ct], 0,0,0);
    }
}

__device__ __forceinline__ void jet_pack(
    const f32x4 (&acc)[2][CH], uint2 (&ph)[2][CH], uint2 (&pl)[2][CH])
{
#pragma unroll
    for (int rt = 0; rt < 2; ++rt) {
        float vf[CH][4];
#pragma unroll
        for (int r = 0; r < 4; ++r) {
            float a, g;  fast_tanh_g(acc[rt][0][r], a, g);
            const float m2a = -2.0f * a;
            vf[0][r] = a;
#pragma unroll
            for (int d = 0; d < 4; ++d) {
                const float zd  = acc[rt][1+d][r];
                const float zdd = acc[rt][5+d][r];
                vf[1+d][r] = g * zd;
                vf[5+d][r] = g * fmaf(m2a*zd, zd, zdd);
            }
        }
#pragma unroll
        for (int ch = 0; ch < CH; ++ch)
            split_pk4(vf[ch][0], vf[ch][1], vf[ch][2], vf[ch][3], ph[rt][ch], pl[rt][ch]);
    }
}

__device__ __forceinline__ void store_act(
    const uint2 (&ph)[2][CH], const uint2 (&pl)[2][CH],
    unsigned short (&act_h)[COLS*KPAD], unsigned short (&act_l)[COLS*KPAD],
    const int lrow0, const int g4, const int p)
{
#pragma unroll
    for (int rt = 0; rt < 2; ++rt) {
        const int n0 = lrow0 + rt*16 + g4;
#pragma unroll
        for (int ch = 0; ch < CH; ++ch) {
            const int off = (ch*SPTS + p)*KPAD + n0;
            *reinterpret_cast<uint2*>(&act_h[off]) = ph[rt][ch];
            *reinterpret_cast<uint2*>(&act_l[off]) = pl[rt][ch];
        }
    }
}

__device__ __forceinline__ void input_jet(
    const float q0, const float q1, const float q2, const float q3,
    const float* __restrict__ uWin, const float* __restrict__ ubin, const int gg,
    uint2 (&ph)[2][CH], uint2 (&pl)[2][CH])
{
#pragma unroll
    for (int c4 = 0; c4 < 2; ++c4) {
        float vf[CH][4];
#pragma unroll
        for (int i = 0; i < 4; ++i) {
            const int n = gg*8 + c4*4 + i;
            const float4 wr = *reinterpret_cast<const float4*>(&uWin[n*4]);
            const float z = ubin[n] + wr.x*q0 + wr.y*q1 + wr.z*q2 + wr.w*q3;
            float a, g;  fast_tanh_g(z, a, g);
            const float m = -2.0f * a * g;
            vf[0][i] = a;
            vf[1][i] = g*wr.x; vf[2][i] = g*wr.y; vf[3][i] = g*wr.z; vf[4][i] = g*wr.w;
            vf[5][i] = m*wr.x*wr.x; vf[6][i] = m*wr.y*wr.y;
            vf[7][i] = m*wr.z*wr.z; vf[8][i] = m*wr.w*wr.w;
        }
#pragma unroll
        for (int ch = 0; ch < CH; ++ch)
            split_pk4(vf[ch][0], vf[ch][1], vf[ch][2], vf[ch][3], ph[c4][ch], pl[c4][ch]);
    }
}

__device__ __forceinline__ void store_input(
    const uint2 (&ph)[2][CH], const uint2 (&pl)[2][CH],
    unsigned short (&act_h)[COLS*KPAD], unsigned short (&act_l)[COLS*KPAD],
    const int gg, const int p)
{
#pragma unroll
    for (int c4 = 0; c4 < 2; ++c4) {
        const int n0 = gg*8 + c4*4;
#pragma unroll
        for (int ch = 0; ch < CH; ++ch) {
            const int off = (ch*SPTS + p)*KPAD + n0;
            *reinterpret_cast<uint2*>(&act_h[off]) = ph[c4][ch];
            *reinterpret_cast<uint2*>(&act_l[off]) = pl[c4][ch];
        }
    }
}

__device__ __forceinline__ void out_parts(
    const f32x4 (&acc)[2][CH], const float* __restrict__ uWout,
    const int lrow0, const int g4,
    float& p0, float& p1, float& p2, float& p3)
{
    p0 = p1 = p2 = p3 = 0.f;
#pragma unroll
    for (int rt = 0; rt < 2; ++rt) {
        const float4 w4 = *reinterpret_cast<const float4*>(&uWout[lrow0 + rt*16 + g4]);
#pragma unroll
        for (int r = 0; r < 4; ++r) {
            const float wr = (&w4.x)[r];
            float a, g;  fast_tanh_g(acc[rt][0][r], a, g);
            const float zd0 = acc[rt][1][r], zd1 = acc[rt][2][r];
            const float zd2 = acc[rt][3][r], zd3 = acc[rt][4][r];
            p0 = fmaf(wr, g*(acc[rt][5][r] - 2.0f*a*zd0*zd0), p0);
            p1 = fmaf(wr, g*(acc[rt][6][r] - 2.0f*a*zd1*zd1), p1);
            p2 = fmaf(wr, g*(acc[rt][7][r] - 2.0f*a*zd2*zd2), p2);
            p3 = fmaf(wr, g*(acc[rt][8][r] - 2.0f*a*zd3*zd3), p3);
        }
    }
    p0 += __shfl_xor(p0, 16); p0 += __shfl_xor(p0, 32);
    p1 += __shfl_xor(p1, 16); p1 += __shfl_xor(p1, 32);
    p2 += __shfl_xor(p2, 16); p2 += __shfl_xor(p2, 32);
    p3 += __shfl_xor(p3, 16); p3 += __shfl_xor(p3, 32);
}

// ---------------- ping-pong MFMA residual kernel (2 sets/block, MFMA(X) ∥ jet(Y)) ----
#define PSUM(rqi, pi, ii) scratch[((rqi)*PPB + (pi))*4 + (ii)]

__global__ __launch_bounds__(256, 2) void resid_mfma(
    const float* __restrict__ gt, const float* __restrict__ gx,
    const float* __restrict__ gy, const float* __restrict__ gz,
    const float* __restrict__ uWin, const float* __restrict__ ubin,
    const float* __restrict__ ubhid, const float* __restrict__ uWout,
    const unsigned short* __restrict__ whi, const unsigned short* __restrict__ wlo,
    const float* __restrict__ pWin, const float* __restrict__ pbin,
    const float* __restrict__ pWhid, const float* __restrict__ pbhid,
    const float* __restrict__ pWout, const float* __restrict__ pbout,
    float* __restrict__ out)
{
    __shared__ unsigned short act_h[COLS*KPAD];   // 38016 B (shared by both sets)
    __shared__ unsigned short act_l[COLS*KPAD];   // 38016 B
    __shared__ float pts4[PPB][4];                // 512 B
    __shared__ float scratch[PPB*32];             // 4096 B: psi_h1 (prologue) / psum (epilogue)
    __shared__ float c2s[PPB];                    // 128 B   -> total 80768 B (2 blocks/CU)

    const int tid  = threadIdx.x;
    const int rq   = tid >> 6;          // wave = row quarter
    const int v    = tid & 63;
    const int base = blockIdx.x * PPB;

    if (tid < PPB) {
        pts4[tid][0] = gt[base+tid]; pts4[tid][1] = gx[base+tid];
        pts4[tid][2] = gy[base+tid]; pts4[tid][3] = gz[base+tid];
    }
    __syncthreads();

    const int pI = tid & 15;            // input-layer decomposition: point within set
    const int gg = tid >> 4;            // 0..15, 8 neurons each
    const float qa0 = pts4[pI][0],    qa1 = pts4[pI][1],    qa2 = pts4[pI][2],    qa3 = pts4[pI][3];
    const float qb0 = pts4[16+pI][0], qb1 = pts4[16+pI][1], qb2 = pts4[16+pI][2], qb3 = pts4[16+pI][3];
    const int pp  = tid >> 3;           // psi decomposition: 8 threads/point
    const int sub = tid & 7;

    // ---- prologue: input jet A -> store; psi stage 1 (all 32 points) ----
    {
        uint2 phI[2][CH], plI[2][CH];
        input_jet(qa0, qa1, qa2, qa3, uWin, ubin, gg, phI, plI);
        store_input(phI, plI, act_h, act_l, gg, pI);
    }
    {
        const float q0 = pts4[pp][0], q1 = pts4[pp][1], q2 = pts4[pp][2], q3 = pts4[pp][3];
#pragma unroll
        for (int rr = 0; rr < 4; ++rr) {
            const int r = sub*4 + rr;
            const float4 wr = *reinterpret_cast<const float4*>(&pWin[r*4]);
            float a, gd;
            fast_tanh_g(pbin[r] + wr.x*q0 + wr.y*q1 + wr.z*q2 + wr.w*q3, a, gd);
            scratch[pp*32 + r] = a;
        }
    }
    __syncthreads();

    const int g4    = (v >> 4) << 2;
    const int lrow0 = rq * 32;
    const int bcol  = v & 15;
    const int krow  = (v >> 4) << 3;

    f32x4 accA[2][CH], accB[2][CH];
    uint2 phA[2][CH], plA[2][CH], phB[2][CH], plB[2][CH];

    // ---- W1: MFMA_A(0)  ∥  input jet B + psi stage 2 ----
    mfma_layer(accA, whi, wlo, act_h, act_l, ubhid, 0, lrow0, g4, rq, v, bcol, krow);
    input_jet(qb0, qb1, qb2, qb3, uWin, ubin, gg, phB, plB);
    {
        float partial = 0.f;
#pragma unroll
        for (int rr = 0; rr < 4; ++rr) {
            const int r = sub*4 + rr;
            float s = pbhid[r];
#pragma unroll
            for (int j = 0; j < 32; ++j) s = fmaf(pWhid[r*32+j], scratch[pp*32 + j], s);
            float a, gd;  fast_tanh_g(s, a, gd);
            partial = fmaf(pWout[r], a, partial);
        }
        partial += __shfl_xor(partial, 1);
        partial += __shfl_xor(partial, 2);
        partial += __shfl_xor(partial, 4);
        if (sub == 0) {
            const float c = 1.0f + pbout[0] + partial;
            c2s[pp] = c * c;
        }
    }

    // ---- main ping-pong: each window = MFMA of one set ∥ jet of the other ----
    for (int l = 0; l < 4; ++l) {
        __syncthreads();                       // MFMA_A(l)'s act reads complete
        if (l == 0) store_input(phB, plB, act_h, act_l, gg, pI);
        else        store_act  (phB, plB, act_h, act_l, lrow0, g4, bcol);
        __syncthreads();
        mfma_layer(accB, whi, wlo, act_h, act_l, ubhid, l, lrow0, g4, rq, v, bcol, krow);
        jet_pack(accA, phA, plA);              // set A act(l+1), overlaps MFMA_B(l)
        __syncthreads();                       // MFMA_B(l)'s act reads complete
        store_act(phA, plA, act_h, act_l, lrow0, g4, bcol);
        __syncthreads();
        mfma_layer(accA, whi, wlo, act_h, act_l, ubhid, l+1, lrow0, g4, rq, v, bcol, krow);
        jet_pack(accB, phB, plB);              // set B act(l+1), overlaps MFMA_A(l+1)
    }

    // ---- tail: last B layer ∥ output-layer partials for A ----
    __syncthreads();
    store_act(phB, plB, act_h, act_l, lrow0, g4, bcol);
    __syncthreads();
    mfma_layer(accB, whi, wlo, act_h, act_l, ubhid, 4, lrow0, g4, rq, v, bcol, krow);
    float a0, a1, a2, a3;
    out_parts(accA, uWout, lrow0, g4, a0, a1, a2, a3);   // overlaps MFMA_B(4)
    if (v < 16) {
        PSUM(rq, v, 0) = a0; PSUM(rq, v, 1) = a1;
        PSUM(rq, v, 2) = a2; PSUM(rq, v, 3) = a3;
    }
    __syncthreads();                           // psum(A) visible; accB(4) done
    float b0, b1, b2, b3;
    out_parts(accB, uWout, lrow0, g4, b0, b1, b2, b3);
    if (v < 16) {
        PSUM(rq, 16+v, 0) = b0; PSUM(rq, 16+v, 1) = b1;
        PSUM(rq, 16+v, 2) = b2; PSUM(rq, 16+v, 3) = b3;
    }
    if (tid < 16) {                            // final reduce set A
        const float d0  = PSUM(0,tid,0) + PSUM(1,tid,0) + PSUM(2,tid,0) + PSUM(3,tid,0);
        const float lap = (PSUM(0,tid,1) + PSUM(1,tid,1) + PSUM(2,tid,1) + PSUM(3,tid,1))
                        + (PSUM(0,tid,2) + PSUM(1,tid,2) + PSUM(2,tid,2) + PSUM(3,tid,2))
                        + (PSUM(0,tid,3) + PSUM(1,tid,3) + PSUM(2,tid,3) + PSUM(3,tid,3));
        out[base+tid] = d0 - c2s[tid]*lap;
    }
    __syncthreads();                           // psum(B) visible
    if (tid < 16) {                            // final reduce set B
        const int p = 16 + tid;
        const float d0  = PSUM(0,p,0) + PSUM(1,p,0) + PSUM(2,p,0) + PSUM(3,p,0);
        const float lap = (PSUM(0,p,1) + PSUM(1,p,1) + PSUM(2,p,1) + PSUM(3,p,1))
                        + (PSUM(0,p,2) + PSUM(1,p,2) + PSUM(2,p,2) + PSUM(3,p,2))
                        + (PSUM(0,p,3) + PSUM(1,p,3) + PSUM(2,p,3) + PSUM(3,p,3));
        out[base+p] = d0 - c2s[p]*lap;
    }
}

// ---------------- fallback path (fp32, verified round 1) ----------------
__global__ __launch_bounds__(64) void psi_kernel(
    const float* __restrict__ gt, const float* __restrict__ gx,
    const float* __restrict__ gy, const float* __restrict__ gz,
    const float* __restrict__ pWin, const float* __restrict__ pbin,
    const float* __restrict__ pWhid, const float* __restrict__ pbhid,
    const float* __restrict__ pWout, const float* __restrict__ pbout,
    float* __restrict__ c2)
{
    const int i = blockIdx.x * 64 + threadIdx.x;
    if (i >= N_PTS) return;
    const float q0 = gt[i], q1 = gx[i], q2 = gy[i], q3 = gz[i];
    float h1[32];
#pragma unroll
    for (int r = 0; r < 32; ++r) {
        float s = pbin[r] + pWin[r*4+0]*q0 + pWin[r*4+1]*q1
                + pWin[r*4+2]*q2 + pWin[r*4+3]*q3;
        h1[r] = tanhf(s);
    }
    float psi = pbout[0];
#pragma unroll 4
    for (int r = 0; r < 32; ++r) {
        float s = pbhid[r];
#pragma unroll
        for (int j = 0; j < 32; ++j) s = fmaf(pWhid[r*32+j], h1[j], s);
        psi = fmaf(pWout[r], tanhf(s), psi);
    }
    const float c = 1.0f + psi;
    c2[i] = c * c;
}

__global__ __launch_bounds__(256, 2) void resid_f32(
    const float* __restrict__ gt, const float* __restrict__ gx,
    const float* __restrict__ gy, const float* __restrict__ gz,
    const float* __restrict__ uWin, const float* __restrict__ ubin,
    const float* __restrict__ uWhid, const float* __restrict__ ubhid,
    const float* __restrict__ uWout,
    const float* __restrict__ c2g, float* __restrict__ out)
{
    __shared__ float act[WID][16*CH];
    __shared__ float ptsh[16][4];
    __shared__ float dsh[16][4];
    const int tid  = threadIdx.x;
    const int rg   = tid >> 4;
    const int p    = tid & 15;
    const int base = blockIdx.x * 16;
    const int row0 = rg * 8;
    const int c0   = p * CH;
    if (tid < 16) {
        ptsh[tid][0] = gt[base+tid]; ptsh[tid][1] = gx[base+tid];
        ptsh[tid][2] = gy[base+tid]; ptsh[tid][3] = gz[base+tid];
    }
    __syncthreads();
    {
        const float q0 = ptsh[p][0], q1 = ptsh[p][1], q2 = ptsh[p][2], q3 = ptsh[p][3];
#pragma unroll
        for (int r = 0; r < 8; ++r) {
            const int row = row0 + r;
            const float w0 = uWin[row*4+0], w1 = uWin[row*4+1];
            const float w2 = uWin[row*4+2], w3 = uWin[row*4+3];
            const float zz = ubin[row] + w0*q0 + w1*q1 + w2*q2 + w3*q3;
            const float a  = tanhf(zz);
            const float g  = 1.0f - a*a;
            const float m2 = -2.0f * a * g;
            act[row][c0+0] = a;
            act[row][c0+1] = g*w0; act[row][c0+2] = g*w1;
            act[row][c0+3] = g*w2; act[row][c0+4] = g*w3;
            act[row][c0+5] = m2*w0*w0; act[row][c0+6] = m2*w1*w1;
            act[row][c0+7] = m2*w2*w2; act[row][c0+8] = m2*w3*w3;
        }
    }
    __syncthreads();
    for (int l = 0; l < NHID; ++l) {
        const float* __restrict__ Wl = uWhid + l*WID*WID;
        float accv[8][CH];
#pragma unroll
        for (int r = 0; r < 8; ++r) {
            accv[r][0] = ubhid[l*WID + row0 + r];
#pragma unroll
            for (int c = 1; c < CH; ++c) accv[r][c] = 0.0f;
        }
        for (int k0 = 0; k0 < WID; k0 += 4) {
            float4 wv[8];
#pragma unroll
            for (int r = 0; r < 8; ++r)
                wv[r] = *reinterpret_cast<const float4*>(&Wl[(row0+r)*WID + k0]);
            float hv[4][CH];
#pragma unroll
            for (int kk = 0; kk < 4; ++kk)
#pragma unroll
                for (int c = 0; c < CH; ++c) hv[kk][c] = act[k0+kk][c0+c];
#pragma unroll
            for (int kk = 0; kk < 4; ++kk)
#pragma unroll
                for (int r = 0; r < 8; ++r) {
                    const float wk = reinterpret_cast<const float*>(&wv[r])[kk];
#pragma unroll
                    for (int c = 0; c < CH; ++c) accv[r][c] = fmaf(wk, hv[kk][c], accv[r][c]);
                }
        }
        __syncthreads();
#pragma unroll
        for (int r = 0; r < 8; ++r) {
            const int row = row0 + r;
            const float a = tanhf(accv[r][0]);
            const float g = 1.0f - a*a;
            act[row][c0+0] = a;
#pragma unroll
            for (int i = 0; i < 4; ++i) {
                const float zd  = accv[r][1+i];
                const float zdd = accv[r][5+i];
                act[row][c0+1+i] = g*zd;
                act[row][c0+5+i] = g*(zdd - 2.0f*a*zd*zd);
            }
        }
        __syncthreads();
    }
    if (tid < 64) {
        const int pp = tid >> 2, ii = tid & 3;
        float s = 0.0f;
        for (int k = 0; k < WID; ++k) s = fmaf(uWout[k], act[k][pp*CH+5+ii], s);
        dsh[pp][ii] = s;
    }
    __syncthreads();
    if (tid < 16) {
        const float d0  = dsh[tid][0];
        const float lap = dsh[tid][1] + dsh[tid][2] + dsh[tid][3];
        out[base+tid] = d0 - c2g[base+tid]*lap;
    }
}

extern "C" void kernel_launch(void* const* d_in, const int* in_sizes, int n_in,
                              void* d_out, int out_size, void* d_ws, size_t ws_size,
                              hipStream_t stream)
{
    const float* gt    = (const float*)d_in[0];
    const float* gx    = (const float*)d_in[1];
    const float* gy    = (const float*)d_in[2];
    const float* gz    = (const float*)d_in[3];
    const float* uWin  = (const float*)d_in[4];
    const float* ubin  = (const float*)d_in[5];
    const float* uWhid = (const float*)d_in[6];
    const float* ubhid = (const float*)d_in[7];
    const float* uWout = (const float*)d_in[8];
    const float* pWin  = (const float*)d_in[10];
    const float* pbin  = (const float*)d_in[11];
    const float* pWhid = (const float*)d_in[12];
    const float* pbhid = (const float*)d_in[13];
    const float* pWout = (const float*)d_in[14];
    const float* pbout = (const float*)d_in[15];
    float* out = (float*)d_out;

    if (ws_size >= 327680) {
        unsigned short* whi = (unsigned short*)d_ws;
        unsigned short* wlo = whi + 81920;                       // 160 KB in
        pack_w<<<160, 64, 0, stream>>>(uWhid, whi, wlo);
        resid_mfma<<<NBLK, 256, 0, stream>>>(gt, gx, gy, gz,
                uWin, ubin, ubhid, uWout, whi, wlo,
                pWin, pbin, pWhid, pbhid, pWout, pbout, out);
    } else {
        float* c2 = (float*)d_ws;
        psi_kernel<<<N_PTS/64, 64, 0, stream>>>(gt, gx, gy, gz,
                pWin, pbin, pWhid, pbhid, pWout, pbout, c2);
        resid_f32<<<N_PTS/16, 256, 0, stream>>>(gt, gx, gy, gz,
                uWin, ubin, uWhid, ubhid, uWout, c2, out);
    }
}

// Round 12
// 77.487 us; speedup vs baseline: 2.6318x; 2.6318x over previous
//
#include <hip/hip_runtime.h>
#include <math.h>

#define N_PTS 16384
#define WID   128
#define NHID  5
#define PPB   16            // points per block
#define CH    9
#define COLS  (PPB*CH)      // 144
#define KPAD  132           // stride 66 dwords == 2 mod 32 -> conflict-free b128 column reads
#define NBLK  (N_PTS/PPB)   // 1024

typedef __attribute__((ext_vector_type(8))) __bf16 bf16x8;
typedef __attribute__((ext_vector_type(4))) float  f32x4;

__device__ __forceinline__ unsigned short f2bf(float x) {
    unsigned int u = __builtin_bit_cast(unsigned int, x);
    u += 0x7FFFu + ((u >> 16) & 1u);          // RNE (no NaNs in this problem)
    return (unsigned short)(u >> 16);
}
__device__ __forceinline__ float bf2f(unsigned short h) {
    unsigned int u = ((unsigned int)h) << 16;
    return __builtin_bit_cast(float, u);
}
// fallback-path split
__device__ __forceinline__ void split_bf(float x, unsigned short& hi, unsigned short& lo) {
    const unsigned int u = __builtin_bit_cast(unsigned int, x);
    hi = (unsigned short)(u >> 16);
    const float rem = x - __builtin_bit_cast(float, u & 0xFFFF0000u);
    lo = (unsigned short)(__builtin_bit_cast(unsigned int, rem) >> 16);
}
// packed bf16 convert: D[15:0]=bf16(v0), D[31:16]=bf16(v1)  (RNE)
__device__ __forceinline__ unsigned int cvtpk(float v0, float v1) {
    unsigned int r;
    asm("v_cvt_pk_bf16_f32 %0, %1, %2" : "=v"(r) : "v"(v0), "v"(v1));
    return r;
}
// split 4 floats into packed hi pair + packed lo pair (lo = exact residual of RNE hi)
__device__ __forceinline__ void split_pk4(const float v0, const float v1,
                                          const float v2, const float v3,
                                          uint2& ph, uint2& pl) {
    const unsigned int h01 = cvtpk(v0, v1);
    const unsigned int h23 = cvtpk(v2, v3);
    const float f0 = __builtin_bit_cast(float, h01 << 16);
    const float f1 = __builtin_bit_cast(float, h01 & 0xFFFF0000u);
    const float f2 = __builtin_bit_cast(float, h23 << 16);
    const float f3 = __builtin_bit_cast(float, h23 & 0xFFFF0000u);
    ph = make_uint2(h01, h23);
    pl = make_uint2(cvtpk(v0 - f0, v1 - f1), cvtpk(v2 - f2, v3 - f3));
}
// a = tanh(x), g = 1 - a^2 (cancellation-free)
__device__ __forceinline__ void fast_tanh_g(float x, float& a, float& g) {
    x = fminf(fmaxf(x, -40.0f), 40.0f);
    const float e = __builtin_amdgcn_exp2f(2.88539008177793f * x);   // exp(2x)
    const float r = __builtin_amdgcn_rcpf(e + 1.0f);
    a = 1.0f - 2.0f * r;
    g = 4.0f * e * r * r;
}

// ---------------- pack uW_hid into MFMA fragment order (bf16 hi/lo) ----------------
// frag f = (l*4+s)*8 + rtg ; lane v supplies A[row = rtg*16 + (v&15)][k = s*32 + (v>>4)*8 + j]
__global__ __launch_bounds__(64) void pack_w(const float* __restrict__ uWhid,
                                             unsigned short* __restrict__ whi,
                                             unsigned short* __restrict__ wlo)
{
    const int f  = blockIdx.x;            // 0..159
    const int v  = threadIdx.x;           // 0..63
    const int l  = f >> 5;
    const int s  = (f >> 3) & 3;
    const int rt = f & 7;
    const int row = rt*16 + (v & 15);
    const int k0  = s*32 + ((v >> 4) << 3);
    const float* src = uWhid + (l*WID + row)*WID + k0;
    unsigned short h[8], lo[8];
#pragma unroll
    for (int j = 0; j < 8; ++j) {
        const float x = src[j];
        h[j]  = f2bf(x);
        lo[j] = f2bf(x - bf2f(h[j]));
    }
    const int off = f*512 + v*8;
    *reinterpret_cast<ushort4*>(&whi[off])   = make_ushort4(h[0],h[1],h[2],h[3]);
    *reinterpret_cast<ushort4*>(&whi[off+4]) = make_ushort4(h[4],h[5],h[6],h[7]);
    *reinterpret_cast<ushort4*>(&wlo[off])   = make_ushort4(lo[0],lo[1],lo[2],lo[3]);
    *reinterpret_cast<ushort4*>(&wlo[off+4]) = make_ushort4(lo[4],lo[5],lo[6],lo[7]);
}

// ---------------- MFMA residual kernel (psi fused, 4 waves, 16 pts/block, 2 blk/CU) ----
// Wave w = rq in [0,4): rows [rq*32, rq*32+32) as 2 row-tiles, all 16 points.
// act[col][k] col-major in LDS, col = ch*16 + p, bf16 hi/lo.
__global__ __launch_bounds__(256, 2) void resid_mfma(
    const float* __restrict__ gt, const float* __restrict__ gx,
    const float* __restrict__ gy, const float* __restrict__ gz,
    const float* __restrict__ uWin, const float* __restrict__ ubin,
    const float* __restrict__ ubhid, const float* __restrict__ uWout,
    const unsigned short* __restrict__ whi, const unsigned short* __restrict__ wlo,
    const float* __restrict__ pWin, const float* __restrict__ pbin,
    const float* __restrict__ pWhid, const float* __restrict__ pbhid,
    const float* __restrict__ pWout, const float* __restrict__ pbout,
    float* __restrict__ out)
{
    __shared__ unsigned short act_h[COLS*KPAD];   // 38016 B
    __shared__ unsigned short act_l[COLS*KPAD];   // 38016 B
    __shared__ float pts4[PPB][4];                // 256 B
    __shared__ float psi_h1[PPB][32];             // 2048 B
    __shared__ float c2s[PPB];                    // 64 B
    __shared__ float psum[4][PPB][4];             // 1024 B   -> total 79424 B (2 blocks/CU)

    const int tid  = threadIdx.x;
    const int rq   = tid >> 6;          // wave = row quarter
    const int v    = tid & 63;
    const int base = blockIdx.x * PPB;

    if (tid < PPB) {
        pts4[tid][0] = gt[base+tid]; pts4[tid][1] = gx[base+tid];
        pts4[tid][2] = gy[base+tid]; pts4[tid][3] = gz[base+tid];
    }
    __syncthreads();

    // ---- input layer 4 -> 128 (256 threads: 16 pt x 16 neuron-groups of 8) ----
    {
        const int p  = tid & 15;
        const int gg = tid >> 4;            // 0..15
        const float q0 = pts4[p][0], q1 = pts4[p][1], q2 = pts4[p][2], q3 = pts4[p][3];
#pragma unroll
        for (int c4 = 0; c4 < 2; ++c4) {
            float vf[CH][4];
#pragma unroll
            for (int i = 0; i < 4; ++i) {
                const int n = gg*8 + c4*4 + i;
                const float4 wr = *reinterpret_cast<const float4*>(&uWin[n*4]);
                const float z = ubin[n] + wr.x*q0 + wr.y*q1 + wr.z*q2 + wr.w*q3;
                float a, g;  fast_tanh_g(z, a, g);
                const float m = -2.0f * a * g;
                vf[0][i] = a;
                vf[1][i] = g*wr.x; vf[2][i] = g*wr.y; vf[3][i] = g*wr.z; vf[4][i] = g*wr.w;
                vf[5][i] = m*wr.x*wr.x; vf[6][i] = m*wr.y*wr.y;
                vf[7][i] = m*wr.z*wr.z; vf[8][i] = m*wr.w*wr.w;
            }
            const int n0 = gg*8 + c4*4;
#pragma unroll
            for (int ch = 0; ch < CH; ++ch) {
                uint2 ph, pl;
                split_pk4(vf[ch][0], vf[ch][1], vf[ch][2], vf[ch][3], ph, pl);
                const int off = (ch*PPB + p)*KPAD + n0;
                *reinterpret_cast<uint2*>(&act_h[off]) = ph;
                *reinterpret_cast<uint2*>(&act_l[off]) = pl;
            }
        }
    }
    // ---- psi stage 1: h1 = tanh(pW_in . pt + pb_in), 16 threads per point ----
    {
        const int p = tid >> 4, sub = tid & 15;
        const float q0 = pts4[p][0], q1 = pts4[p][1], q2 = pts4[p][2], q3 = pts4[p][3];
#pragma unroll
        for (int rr = 0; rr < 2; ++rr) {
            const int r = sub*2 + rr;
            const float4 wr = *reinterpret_cast<const float4*>(&pWin[r*4]);
            float a, gd;
            fast_tanh_g(pbin[r] + wr.x*q0 + wr.y*q1 + wr.z*q2 + wr.w*q3, a, gd);
            psi_h1[p][r] = a;
        }
    }
    __syncthreads();

    // ---- psi stage 2: c2 = (1 + psi)^2 ----
    {
        const int p = tid >> 4, sub = tid & 15;
        float partial = 0.f;
#pragma unroll
        for (int rr = 0; rr < 2; ++rr) {
            const int r = sub*2 + rr;
            float s = pbhid[r];
#pragma unroll
            for (int j = 0; j < 32; ++j) s = fmaf(pWhid[r*32+j], psi_h1[p][j], s);
            float a, gd;  fast_tanh_g(s, a, gd);
            partial = fmaf(pWout[r], a, partial);
        }
        partial += __shfl_xor(partial, 1);
        partial += __shfl_xor(partial, 2);
        partial += __shfl_xor(partial, 4);
        partial += __shfl_xor(partial, 8);
        if (sub == 0) {
            const float c = 1.0f + pbout[0] + partial;
            c2s[p] = c * c;
        }
    }

    // ---- 5 hidden layers via MFMA (fully unrolled: compile-time l lets the
    //      compiler hoist next layer's GLOBAL weight loads into the jet phase) ----
    f32x4 acc[2][CH];
    const int g4    = (v >> 4) << 2;          // D-row base within tile
    const int lrow0 = rq * 32;
    const int bcol  = v & 15;                 // point index
    const int krow  = (v >> 4) << 3;

#pragma unroll
    for (int l = 0; l < NHID; ++l) {
#pragma unroll
        for (int rt = 0; rt < 2; ++rt) {
            acc[rt][0] = *reinterpret_cast<const f32x4*>(&ubhid[l*WID + lrow0 + rt*16 + g4]);
#pragma unroll
            for (int ct = 1; ct < CH; ++ct) acc[rt][ct] = (f32x4){0.f,0.f,0.f,0.f};
        }
#pragma unroll
        for (int s = 0; s < 4; ++s) {
            bf16x8 bh[CH], bl[CH], ah[2], al[2];
            const int kof = s*32 + krow;
            const int fb  = ((l*4 + s)*8 + rq*2)*512 + v*8;
#pragma unroll
            for (int rt = 0; rt < 2; ++rt) {
                ah[rt] = *reinterpret_cast<const bf16x8*>(&whi[fb + rt*512]);
                al[rt] = *reinterpret_cast<const bf16x8*>(&wlo[fb + rt*512]);
            }
#pragma unroll
            for (int ct = 0; ct < CH; ++ct) {
                const int off = (ct*PPB + bcol)*KPAD + kof;
                bh[ct] = *reinterpret_cast<const bf16x8*>(&act_h[off]);
                bl[ct] = *reinterpret_cast<const bf16x8*>(&act_l[off]);
            }
            __builtin_amdgcn_s_setprio(1);
            // group 1: Whi x Ahi
#pragma unroll
            for (int rt = 0; rt < 2; ++rt)
#pragma unroll
                for (int ct = 0; ct < CH; ++ct)
                    acc[rt][ct] = __builtin_amdgcn_mfma_f32_16x16x32_bf16(ah[rt], bh[ct], acc[rt][ct], 0,0,0);
            // group 2: Whi x Alo
#pragma unroll
            for (int rt = 0; rt < 2; ++rt)
#pragma unroll
                for (int ct = 0; ct < CH; ++ct)
                    acc[rt][ct] = __builtin_amdgcn_mfma_f32_16x16x32_bf16(ah[rt], bl[ct], acc[rt][ct], 0,0,0);
            // group 3: Wlo x Ahi
#pragma unroll
            for (int rt = 0; rt < 2; ++rt)
#pragma unroll
                for (int ct = 0; ct < CH; ++ct)
                    acc[rt][ct] = __builtin_amdgcn_mfma_f32_16x16x32_bf16(al[rt], bh[ct], acc[rt][ct], 0,0,0);
            __builtin_amdgcn_s_setprio(0);
        }

        if (l < NHID-1) {
            // ---- jet nonlinearity + split, ALL in registers, BEFORE the barrier ----
            const int p = v & 15;
            uint2 ph[2][CH], pl[2][CH];
#pragma unroll
            for (int rt = 0; rt < 2; ++rt) {
                float vf[CH][4];
#pragma unroll
                for (int r = 0; r < 4; ++r) {
                    float a, g;  fast_tanh_g(acc[rt][0][r], a, g);
                    const float m2a = -2.0f * a;
                    vf[0][r] = a;
#pragma unroll
                    for (int d = 0; d < 4; ++d) {
                        const float zd  = acc[rt][1+d][r];
                        const float zdd = acc[rt][5+d][r];
                        vf[1+d][r] = g * zd;
                        vf[5+d][r] = g * fmaf(m2a*zd, zd, zdd);
                    }
                }
#pragma unroll
                for (int ch = 0; ch < CH; ++ch)
                    split_pk4(vf[ch][0], vf[ch][1], vf[ch][2], vf[ch][3], ph[rt][ch], pl[rt][ch]);
            }
            __syncthreads();   // all reads of act done before overwrite
#pragma unroll
            for (int rt = 0; rt < 2; ++rt) {
                const int n0 = lrow0 + rt*16 + g4;
#pragma unroll
                for (int ch = 0; ch < CH; ++ch) {
                    const int off = (ch*PPB + p)*KPAD + n0;
                    *reinterpret_cast<uint2*>(&act_h[off]) = ph[rt][ch];
                    *reinterpret_cast<uint2*>(&act_l[off]) = pl[rt][ch];
                }
            }
            __syncthreads();
        }
    }

    // ---- output layer: d_i = uWout . a''_i, jet fused, in-register ----
    float part0 = 0.f, part1 = 0.f, part2 = 0.f, part3 = 0.f;
#pragma unroll
    for (int rt = 0; rt < 2; ++rt) {
        const float4 w4 = *reinterpret_cast<const float4*>(&uWout[lrow0 + rt*16 + g4]);
#pragma unroll
        for (int r = 0; r < 4; ++r) {
            const float wr = (&w4.x)[r];
            float a, g;  fast_tanh_g(acc[rt][0][r], a, g);
            const float zd0 = acc[rt][1][r], zd1 = acc[rt][2][r];
            const float zd2 = acc[rt][3][r], zd3 = acc[rt][4][r];
            part0 = fmaf(wr, g*(acc[rt][5][r] - 2.0f*a*zd0*zd0), part0);
            part1 = fmaf(wr, g*(acc[rt][6][r] - 2.0f*a*zd1*zd1), part1);
            part2 = fmaf(wr, g*(acc[rt][7][r] - 2.0f*a*zd2*zd2), part2);
            part3 = fmaf(wr, g*(acc[rt][8][r] - 2.0f*a*zd3*zd3), part3);
        }
    }
    part0 += __shfl_xor(part0, 16); part0 += __shfl_xor(part0, 32);
    part1 += __shfl_xor(part1, 16); part1 += __shfl_xor(part1, 32);
    part2 += __shfl_xor(part2, 16); part2 += __shfl_xor(part2, 32);
    part3 += __shfl_xor(part3, 16); part3 += __shfl_xor(part3, 32);
    if (v < PPB) {
        psum[rq][v][0] = part0; psum[rq][v][1] = part1;
        psum[rq][v][2] = part2; psum[rq][v][3] = part3;
    }
    __syncthreads();
    if (tid < PPB) {
        const float d0  = psum[0][tid][0] + psum[1][tid][0] + psum[2][tid][0] + psum[3][tid][0];
        const float lap = (psum[0][tid][1] + psum[1][tid][1] + psum[2][tid][1] + psum[3][tid][1])
                        + (psum[0][tid][2] + psum[1][tid][2] + psum[2][tid][2] + psum[3][tid][2])
                        + (psum[0][tid][3] + psum[1][tid][3] + psum[2][tid][3] + psum[3][tid][3]);
        out[base+tid] = d0 - c2s[tid]*lap;
    }
}

// ---------------- fallback path (fp32, verified round 1) ----------------
__global__ __launch_bounds__(64) void psi_kernel(
    const float* __restrict__ gt, const float* __restrict__ gx,
    const float* __restrict__ gy, const float* __restrict__ gz,
    const float* __restrict__ pWin, const float* __restrict__ pbin,
    const float* __restrict__ pWhid, const float* __restrict__ pbhid,
    const float* __restrict__ pWout, const float* __restrict__ pbout,
    float* __restrict__ c2)
{
    const int i = blockIdx.x * 64 + threadIdx.x;
    if (i >= N_PTS) return;
    const float q0 = gt[i], q1 = gx[i], q2 = gy[i], q3 = gz[i];
    float h1[32];
#pragma unroll
    for (int r = 0; r < 32; ++r) {
        float s = pbin[r] + pWin[r*4+0]*q0 + pWin[r*4+1]*q1
                + pWin[r*4+2]*q2 + pWin[r*4+3]*q3;
        h1[r] = tanhf(s);
    }
    float psi = pbout[0];
#pragma unroll 4
    for (int r = 0; r < 32; ++r) {
        float s = pbhid[r];
#pragma unroll
        for (int j = 0; j < 32; ++j) s = fmaf(pWhid[r*32+j], h1[j], s);
        psi = fmaf(pWout[r], tanhf(s), psi);
    }
    const float c = 1.0f + psi;
    c2[i] = c * c;
}

__global__ __launch_bounds__(256, 2) void resid_f32(
    const float* __restrict__ gt, const float* __restrict__ gx,
    const float* __restrict__ gy, const float* __restrict__ gz,
    const float* __restrict__ uWin, const float* __restrict__ ubin,
    const float* __restrict__ uWhid, const float* __restrict__ ubhid,
    const float* __restrict__ uWout,
    const float* __restrict__ c2g, float* __restrict__ out)
{
    __shared__ float act[WID][16*CH];
    __shared__ float ptsh[16][4];
    __shared__ float dsh[16][4];
    const int tid  = threadIdx.x;
    const int rg   = tid >> 4;
    const int p    = tid & 15;
    const int base = blockIdx.x * 16;
    const int row0 = rg * 8;
    const int c0   = p * CH;
    if (tid < 16) {
        ptsh[tid][0] = gt[base+tid]; ptsh[tid][1] = gx[base+tid];
        ptsh[tid][2] = gy[base+tid]; ptsh[tid][3] = gz[base+tid];
    }
    __syncthreads();
    {
        const float q0 = ptsh[p][0], q1 = ptsh[p][1], q2 = ptsh[p][2], q3 = ptsh[p][3];
#pragma unroll
        for (int r = 0; r < 8; ++r) {
            const int row = row0 + r;
            const float w0 = uWin[row*4+0], w1 = uWin[row*4+1];
            const float w2 = uWin[row*4+2], w3 = uWin[row*4+3];
            const float zz = ubin[row] + w0*q0 + w1*q1 + w2*q2 + w3*q3;
            const float a  = tanhf(zz);
            const float g  = 1.0f - a*a;
            const float m2 = -2.0f * a * g;
            act[row][c0+0] = a;
            act[row][c0+1] = g*w0; act[row][c0+2] = g*w1;
            act[row][c0+3] = g*w2; act[row][c0+4] = g*w3;
            act[row][c0+5] = m2*w0*w0; act[row][c0+6] = m2*w1*w1;
            act[row][c0+7] = m2*w2*w2; act[row][c0+8] = m2*w3*w3;
        }
    }
    __syncthreads();
    for (int l = 0; l < NHID; ++l) {
        const float* __restrict__ Wl = uWhid + l*WID*WID;
        float accv[8][CH];
#pragma unroll
        for (int r = 0; r < 8; ++r) {
            accv[r][0] = ubhid[l*WID + row0 + r];
#pragma unroll
            for (int c = 1; c < CH; ++c) accv[r][c] = 0.0f;
        }
        for (int k0 = 0; k0 < WID; k0 += 4) {
            float4 wv[8];
#pragma unroll
            for (int r = 0; r < 8; ++r)
                wv[r] = *reinterpret_cast<const float4*>(&Wl[(row0+r)*WID + k0]);
            float hv[4][CH];
#pragma unroll
            for (int kk = 0; kk < 4; ++kk)
#pragma unroll
                for (int c = 0; c < CH; ++c) hv[kk][c] = act[k0+kk][c0+c];
#pragma unroll
            for (int kk = 0; kk < 4; ++kk)
#pragma unroll
                for (int r = 0; r < 8; ++r) {
                    const float wk = reinterpret_cast<const float*>(&wv[r])[kk];
#pragma unroll
                    for (int c = 0; c < CH; ++c) accv[r][c] = fmaf(wk, hv[kk][c], accv[r][c]);
                }
        }
        __syncthreads();
#pragma unroll
        for (int r = 0; r < 8; ++r) {
            const int row = row0 + r;
            const float a = tanhf(accv[r][0]);
            const float g = 1.0f - a*a;
            act[row][c0+0] = a;
#pragma unroll
            for (int i = 0; i < 4; ++i) {
                const float zd  = accv[r][1+i];
                const float zdd = accv[r][5+i];
                act[row][c0+1+i] = g*zd;
                act[row][c0+5+i] = g*(zdd - 2.0f*a*zd*zd);
            }
        }
        __syncthreads();
    }
    if (tid < 64) {
        const int pp = tid >> 2, ii = tid & 3;
        float s = 0.0f;
        for (int k = 0; k < WID; ++k) s = fmaf(uWout[k], act[k][pp*CH+5+ii], s);
        dsh[pp][ii] = s;
    }
    __syncthreads();
    if (tid < 16) {
        const float d0  = dsh[tid][0];
        const float lap = dsh[tid][1] + dsh[tid][2] + dsh[tid][3];
        out[base+tid] = d0 - c2g[base+tid]*lap;
    }
}

extern "C" void kernel_launch(void* const* d_in, const int* in_sizes, int n_in,
                              void* d_out, int out_size, void* d_ws, size_t ws_size,
                              hipStream_t stream)
{
    const float* gt    = (const float*)d_in[0];
    const float* gx    = (const float*)d_in[1];
    const float* gy    = (const float*)d_in[2];
    const float* gz    = (const float*)d_in[3];
    const float* uWin  = (const float*)d_in[4];
    const float* ubin  = (const float*)d_in[5];
    const float* uWhid = (const float*)d_in[6];
    const float* ubhid = (const float*)d_in[7];
    const float* uWout = (const float*)d_in[8];
    const float* pWin  = (const float*)d_in[10];
    const float* pbin  = (const float*)d_in[11];
    const float* pWhid = (const float*)d_in[12];
    const float* pbhid = (const float*)d_in[13];
    const float* pWout = (const float*)d_in[14];
    const float* pbout = (const float*)d_in[15];
    float* out = (float*)d_out;

    if (ws_size >= 327680) {
        unsigned short* whi = (unsigned short*)d_ws;
        unsigned short* wlo = whi + 81920;                       // 160 KB in
        pack_w<<<160, 64, 0, stream>>>(uWhid, whi, wlo);
        resid_mfma<<<NBLK, 256, 0, stream>>>(gt, gx, gy, gz,
                uWin, ubin, ubhid, uWout, whi, wlo,
                pWin, pbin, pWhid, pbhid, pWout, pbout, out);
    } else {
        float* c2 = (float*)d_ws;
        psi_kernel<<<N_PTS/64, 64, 0, stream>>>(gt, gx, gy, gz,
                pWin, pbin, pWhid, pbhid, pWout, pbout, c2);
        resid_f32<<<N_PTS/16, 256, 0, stream>>>(gt, gx, gy, gz,
                uWin, ubin, uWhid, ubhid, uWout, c2, out);
    }
}

// Round 13
// 64.663 us; speedup vs baseline: 3.1538x; 1.1983x over previous
//
#include <hip/hip_runtime.h>
#include <math.h>

#define N_PTS 16384
#define WID   128
#define NHID  5
#define PPB   16            // points per block
#define NCH   7             // a, zt', zx', zy', zz', ztt'', zlap''  (lap channels merged)
#define COLS  (PPB*NCH)     // 112
#define KPAD  132           // stride 66 dwords == 2 mod 32 -> conflict-free b128 column reads
#define NBLK  (N_PTS/PPB)   // 1024

typedef __attribute__((ext_vector_type(8))) __bf16 bf16x8;
typedef __attribute__((ext_vector_type(4))) float  f32x4;

__device__ __forceinline__ unsigned short f2bf(float x) {
    unsigned int u = __builtin_bit_cast(unsigned int, x);
    u += 0x7FFFu + ((u >> 16) & 1u);          // RNE (no NaNs in this problem)
    return (unsigned short)(u >> 16);
}
__device__ __forceinline__ float bf2f(unsigned short h) {
    unsigned int u = ((unsigned int)h) << 16;
    return __builtin_bit_cast(float, u);
}
// fallback-path split
__device__ __forceinline__ void split_bf(float x, unsigned short& hi, unsigned short& lo) {
    const unsigned int u = __builtin_bit_cast(unsigned int, x);
    hi = (unsigned short)(u >> 16);
    const float rem = x - __builtin_bit_cast(float, u & 0xFFFF0000u);
    lo = (unsigned short)(__builtin_bit_cast(unsigned int, rem) >> 16);
}
// packed bf16 convert: D[15:0]=bf16(v0), D[31:16]=bf16(v1)  (RNE)
__device__ __forceinline__ unsigned int cvtpk(float v0, float v1) {
    unsigned int r;
    asm("v_cvt_pk_bf16_f32 %0, %1, %2" : "=v"(r) : "v"(v0), "v"(v1));
    return r;
}
// split 4 floats into packed hi pair + packed lo pair (lo = exact residual of RNE hi)
__device__ __forceinline__ void split_pk4(const float v0, const float v1,
                                          const float v2, const float v3,
                                          uint2& ph, uint2& pl) {
    const unsigned int h01 = cvtpk(v0, v1);
    const unsigned int h23 = cvtpk(v2, v3);
    const float f0 = __builtin_bit_cast(float, h01 << 16);
    const float f1 = __builtin_bit_cast(float, h01 & 0xFFFF0000u);
    const float f2 = __builtin_bit_cast(float, h23 << 16);
    const float f3 = __builtin_bit_cast(float, h23 & 0xFFFF0000u);
    ph = make_uint2(h01, h23);
    pl = make_uint2(cvtpk(v0 - f0, v1 - f1), cvtpk(v2 - f2, v3 - f3));
}
// a = tanh(x), g = 1 - a^2 (cancellation-free)
__device__ __forceinline__ void fast_tanh_g(float x, float& a, float& g) {
    x = fminf(fmaxf(x, -40.0f), 40.0f);
    const float e = __builtin_amdgcn_exp2f(2.88539008177793f * x);   // exp(2x)
    const float r = __builtin_amdgcn_rcpf(e + 1.0f);
    a = 1.0f - 2.0f * r;
    g = 4.0f * e * r * r;
}

// ---------------- pack uW_hid into MFMA fragment order (bf16 hi/lo) ----------------
// frag f = (l*4+s)*8 + rtg ; lane v supplies A[row = rtg*16 + (v&15)][k = s*32 + (v>>4)*8 + j]
__global__ __launch_bounds__(64) void pack_w(const float* __restrict__ uWhid,
                                             unsigned short* __restrict__ whi,
                                             unsigned short* __restrict__ wlo)
{
    const int f  = blockIdx.x;            // 0..159
    const int v  = threadIdx.x;           // 0..63
    const int l  = f >> 5;
    const int s  = (f >> 3) & 3;
    const int rt = f & 7;
    const int row = rt*16 + (v & 15);
    const int k0  = s*32 + ((v >> 4) << 3);
    const float* src = uWhid + (l*WID + row)*WID + k0;
    unsigned short h[8], lo[8];
#pragma unroll
    for (int j = 0; j < 8; ++j) {
        const float x = src[j];
        h[j]  = f2bf(x);
        lo[j] = f2bf(x - bf2f(h[j]));
    }
    const int off = f*512 + v*8;
    *reinterpret_cast<ushort4*>(&whi[off])   = make_ushort4(h[0],h[1],h[2],h[3]);
    *reinterpret_cast<ushort4*>(&whi[off+4]) = make_ushort4(h[4],h[5],h[6],h[7]);
    *reinterpret_cast<ushort4*>(&wlo[off])   = make_ushort4(lo[0],lo[1],lo[2],lo[3]);
    *reinterpret_cast<ushort4*>(&wlo[off+4]) = make_ushort4(lo[4],lo[5],lo[6],lo[7]);
}

// ---------------- MFMA residual kernel (7-channel jet, 4 waves, 16 pts, 2 blk/CU) ----
// Wave w = rq in [0,4): rows [rq*32, rq*32+32) as 2 row-tiles, all 16 points.
// act[col][k] col-major in LDS, col = ch*16 + p, bf16 hi/lo.
// Channels: 0=a, 1..4 = g*zdot_i, 5 = a''_tt, 6 = a''_lap (xx+yy+zz summed — linear ops
// commute with the sum, so carrying the Laplacian as ONE channel is exact).
__global__ __launch_bounds__(256, 2) void resid_mfma(
    const float* __restrict__ gt, const float* __restrict__ gx,
    const float* __restrict__ gy, const float* __restrict__ gz,
    const float* __restrict__ uWin, const float* __restrict__ ubin,
    const float* __restrict__ ubhid, const float* __restrict__ uWout,
    const unsigned short* __restrict__ whi, const unsigned short* __restrict__ wlo,
    const float* __restrict__ pWin, const float* __restrict__ pbin,
    const float* __restrict__ pWhid, const float* __restrict__ pbhid,
    const float* __restrict__ pWout, const float* __restrict__ pbout,
    float* __restrict__ out)
{
    __shared__ unsigned short act_h[COLS*KPAD];   // 29568 B
    __shared__ unsigned short act_l[COLS*KPAD];   // 29568 B
    __shared__ float pts4[PPB][4];                // 256 B
    __shared__ float psi_h1[PPB][32];             // 2048 B
    __shared__ float c2s[PPB];                    // 64 B
    __shared__ float psum[4][PPB][2];             // 512 B   -> total ~62 KB (2 blocks/CU)

    const int tid  = threadIdx.x;
    const int rq   = tid >> 6;          // wave = row quarter
    const int v    = tid & 63;
    const int base = blockIdx.x * PPB;

    if (tid < PPB) {
        pts4[tid][0] = gt[base+tid]; pts4[tid][1] = gx[base+tid];
        pts4[tid][2] = gy[base+tid]; pts4[tid][3] = gz[base+tid];
    }
    __syncthreads();

    // ---- input layer 4 -> 128 (256 threads: 16 pt x 16 neuron-groups of 8) ----
    {
        const int p  = tid & 15;
        const int gg = tid >> 4;            // 0..15
        const float q0 = pts4[p][0], q1 = pts4[p][1], q2 = pts4[p][2], q3 = pts4[p][3];
#pragma unroll
        for (int c4 = 0; c4 < 2; ++c4) {
            float vf[NCH][4];
#pragma unroll
            for (int i = 0; i < 4; ++i) {
                const int n = gg*8 + c4*4 + i;
                const float4 wr = *reinterpret_cast<const float4*>(&uWin[n*4]);
                const float z = ubin[n] + wr.x*q0 + wr.y*q1 + wr.z*q2 + wr.w*q3;
                float a, g;  fast_tanh_g(z, a, g);
                const float m = -2.0f * a * g;
                vf[0][i] = a;
                vf[1][i] = g*wr.x; vf[2][i] = g*wr.y; vf[3][i] = g*wr.z; vf[4][i] = g*wr.w;
                vf[5][i] = m*wr.x*wr.x;                                   // tt
                vf[6][i] = m*(wr.y*wr.y + wr.z*wr.z + wr.w*wr.w);         // xx+yy+zz
            }
            const int n0 = gg*8 + c4*4;
#pragma unroll
            for (int ch = 0; ch < NCH; ++ch) {
                uint2 ph, pl;
                split_pk4(vf[ch][0], vf[ch][1], vf[ch][2], vf[ch][3], ph, pl);
                const int off = (ch*PPB + p)*KPAD + n0;
                *reinterpret_cast<uint2*>(&act_h[off]) = ph;
                *reinterpret_cast<uint2*>(&act_l[off]) = pl;
            }
        }
    }
    // ---- psi stage 1: h1 = tanh(pW_in . pt + pb_in), 16 threads per point ----
    {
        const int p = tid >> 4, sub = tid & 15;
        const float q0 = pts4[p][0], q1 = pts4[p][1], q2 = pts4[p][2], q3 = pts4[p][3];
#pragma unroll
        for (int rr = 0; rr < 2; ++rr) {
            const int r = sub*2 + rr;
            const float4 wr = *reinterpret_cast<const float4*>(&pWin[r*4]);
            float a, gd;
            fast_tanh_g(pbin[r] + wr.x*q0 + wr.y*q1 + wr.z*q2 + wr.w*q3, a, gd);
            psi_h1[p][r] = a;
        }
    }
    __syncthreads();

    // ---- psi stage 2: c2 = (1 + psi)^2 ----
    {
        const int p = tid >> 4, sub = tid & 15;
        float partial = 0.f;
#pragma unroll
        for (int rr = 0; rr < 2; ++rr) {
            const int r = sub*2 + rr;
            float s = pbhid[r];
#pragma unroll
            for (int j = 0; j < 32; ++j) s = fmaf(pWhid[r*32+j], psi_h1[p][j], s);
            float a, gd;  fast_tanh_g(s, a, gd);
            partial = fmaf(pWout[r], a, partial);
        }
        partial += __shfl_xor(partial, 1);
        partial += __shfl_xor(partial, 2);
        partial += __shfl_xor(partial, 4);
        partial += __shfl_xor(partial, 8);
        if (sub == 0) {
            const float c = 1.0f + pbout[0] + partial;
            c2s[p] = c * c;
        }
    }

    // ---- 5 hidden layers via MFMA ----
    f32x4 acc[2][NCH];
    const int g4    = (v >> 4) << 2;          // D-row base within tile
    const int lrow0 = rq * 32;
    const int bcol  = v & 15;                 // point index
    const int krow  = (v >> 4) << 3;

    for (int l = 0; l < NHID; ++l) {
#pragma unroll
        for (int rt = 0; rt < 2; ++rt) {
            acc[rt][0] = *reinterpret_cast<const f32x4*>(&ubhid[l*WID + lrow0 + rt*16 + g4]);
#pragma unroll
            for (int ct = 1; ct < NCH; ++ct) acc[rt][ct] = (f32x4){0.f,0.f,0.f,0.f};
        }
#pragma unroll
        for (int s = 0; s < 4; ++s) {
            bf16x8 bh[NCH], bl[NCH], ah[2], al[2];
            const int kof = s*32 + krow;
            const int fb  = ((l*4 + s)*8 + rq*2)*512 + v*8;
#pragma unroll
            for (int rt = 0; rt < 2; ++rt) {
                ah[rt] = *reinterpret_cast<const bf16x8*>(&whi[fb + rt*512]);
                al[rt] = *reinterpret_cast<const bf16x8*>(&wlo[fb + rt*512]);
            }
#pragma unroll
            for (int ct = 0; ct < NCH; ++ct) {
                const int off = (ct*PPB + bcol)*KPAD + kof;
                bh[ct] = *reinterpret_cast<const bf16x8*>(&act_h[off]);
                bl[ct] = *reinterpret_cast<const bf16x8*>(&act_l[off]);
            }
            __builtin_amdgcn_s_setprio(1);
            // group 1: Whi x Ahi
#pragma unroll
            for (int rt = 0; rt < 2; ++rt)
#pragma unroll
                for (int ct = 0; ct < NCH; ++ct)
                    acc[rt][ct] = __builtin_amdgcn_mfma_f32_16x16x32_bf16(ah[rt], bh[ct], acc[rt][ct], 0,0,0);
            // group 2: Whi x Alo
#pragma unroll
            for (int rt = 0; rt < 2; ++rt)
#pragma unroll
                for (int ct = 0; ct < NCH; ++ct)
                    acc[rt][ct] = __builtin_amdgcn_mfma_f32_16x16x32_bf16(ah[rt], bl[ct], acc[rt][ct], 0,0,0);
            // group 3: Wlo x Ahi
#pragma unroll
            for (int rt = 0; rt < 2; ++rt)
#pragma unroll
                for (int ct = 0; ct < NCH; ++ct)
                    acc[rt][ct] = __builtin_amdgcn_mfma_f32_16x16x32_bf16(al[rt], bh[ct], acc[rt][ct], 0,0,0);
            __builtin_amdgcn_s_setprio(0);
        }

        if (l < NHID-1) {
            // ---- jet nonlinearity + split, ALL in registers, BEFORE the barrier ----
            const int p = v & 15;
            uint2 ph[2][NCH], pl[2][NCH];
#pragma unroll
            for (int rt = 0; rt < 2; ++rt) {
                float vf[NCH][4];
#pragma unroll
                for (int r = 0; r < 4; ++r) {
                    float a, g;  fast_tanh_g(acc[rt][0][r], a, g);
                    const float m2a = -2.0f * a;
                    const float zt = acc[rt][1][r], zx = acc[rt][2][r];
                    const float zy = acc[rt][3][r], zz = acc[rt][4][r];
                    vf[0][r] = a;
                    vf[1][r] = g * zt;  vf[2][r] = g * zx;
                    vf[3][r] = g * zy;  vf[4][r] = g * zz;
                    vf[5][r] = g * fmaf(m2a*zt, zt, acc[rt][5][r]);
                    const float s2 = fmaf(zx, zx, fmaf(zy, zy, zz*zz));
                    vf[6][r] = g * fmaf(m2a, s2, acc[rt][6][r]);
                }
#pragma unroll
                for (int ch = 0; ch < NCH; ++ch)
                    split_pk4(vf[ch][0], vf[ch][1], vf[ch][2], vf[ch][3], ph[rt][ch], pl[rt][ch]);
            }
            __syncthreads();   // all reads of act done before overwrite
#pragma unroll
            for (int rt = 0; rt < 2; ++rt) {
                const int n0 = lrow0 + rt*16 + g4;
#pragma unroll
                for (int ch = 0; ch < NCH; ++ch) {
                    const int off = (ch*PPB + p)*KPAD + n0;
                    *reinterpret_cast<uint2*>(&act_h[off]) = ph[rt][ch];
                    *reinterpret_cast<uint2*>(&act_l[off]) = pl[rt][ch];
                }
            }
            __syncthreads();
        }
    }

    // ---- output layer: d_tt and lap, jet fused, in-register ----
    float part0 = 0.f, part1 = 0.f;
#pragma unroll
    for (int rt = 0; rt < 2; ++rt) {
        const float4 w4 = *reinterpret_cast<const float4*>(&uWout[lrow0 + rt*16 + g4]);
#pragma unroll
        for (int r = 0; r < 4; ++r) {
            const float wr = (&w4.x)[r];
            float a, g;  fast_tanh_g(acc[rt][0][r], a, g);
            const float m2a = -2.0f * a;
            const float zt = acc[rt][1][r], zx = acc[rt][2][r];
            const float zy = acc[rt][3][r], zz = acc[rt][4][r];
            part0 = fmaf(wr, g * fmaf(m2a*zt, zt, acc[rt][5][r]), part0);
            const float s2 = fmaf(zx, zx, fmaf(zy, zy, zz*zz));
            part1 = fmaf(wr, g * fmaf(m2a, s2, acc[rt][6][r]), part1);
        }
    }
    part0 += __shfl_xor(part0, 16); part0 += __shfl_xor(part0, 32);
    part1 += __shfl_xor(part1, 16); part1 += __shfl_xor(part1, 32);
    if (v < PPB) {
        psum[rq][v][0] = part0; psum[rq][v][1] = part1;
    }
    __syncthreads();
    if (tid < PPB) {
        const float d0  = psum[0][tid][0] + psum[1][tid][0] + psum[2][tid][0] + psum[3][tid][0];
        const float lap = psum[0][tid][1] + psum[1][tid][1] + psum[2][tid][1] + psum[3][tid][1];
        out[base+tid] = d0 - c2s[tid]*lap;
    }
}

// ---------------- fallback path (fp32, verified round 1; 9-channel) ----------------
__global__ __launch_bounds__(64) void psi_kernel(
    const float* __restrict__ gt, const float* __restrict__ gx,
    const float* __restrict__ gy, const float* __restrict__ gz,
    const float* __restrict__ pWin, const float* __restrict__ pbin,
    const float* __restrict__ pWhid, const float* __restrict__ pbhid,
    const float* __restrict__ pWout, const float* __restrict__ pbout,
    float* __restrict__ c2)
{
    const int i = blockIdx.x * 64 + threadIdx.x;
    if (i >= N_PTS) return;
    const float q0 = gt[i], q1 = gx[i], q2 = gy[i], q3 = gz[i];
    float h1[32];
#pragma unroll
    for (int r = 0; r < 32; ++r) {
        float s = pbin[r] + pWin[r*4+0]*q0 + pWin[r*4+1]*q1
                + pWin[r*4+2]*q2 + pWin[r*4+3]*q3;
        h1[r] = tanhf(s);
    }
    float psi = pbout[0];
#pragma unroll 4
    for (int r = 0; r < 32; ++r) {
        float s = pbhid[r];
#pragma unroll
        for (int j = 0; j < 32; ++j) s = fmaf(pWhid[r*32+j], h1[j], s);
        psi = fmaf(pWout[r], tanhf(s), psi);
    }
    const float c = 1.0f + psi;
    c2[i] = c * c;
}

__global__ __launch_bounds__(256, 2) void resid_f32(
    const float* __restrict__ gt, const float* __restrict__ gx,
    const float* __restrict__ gy, const float* __restrict__ gz,
    const float* __restrict__ uWin, const float* __restrict__ ubin,
    const float* __restrict__ uWhid, const float* __restrict__ ubhid,
    const float* __restrict__ uWout,
    const float* __restrict__ c2g, float* __restrict__ out)
{
    __shared__ float act[WID][16*9];
    __shared__ float ptsh[16][4];
    __shared__ float dsh[16][4];
    const int tid  = threadIdx.x;
    const int rg   = tid >> 4;
    const int p    = tid & 15;
    const int base = blockIdx.x * 16;
    const int row0 = rg * 8;
    const int c0   = p * 9;
    if (tid < 16) {
        ptsh[tid][0] = gt[base+tid]; ptsh[tid][1] = gx[base+tid];
        ptsh[tid][2] = gy[base+tid]; ptsh[tid][3] = gz[base+tid];
    }
    __syncthreads();
    {
        const float q0 = ptsh[p][0], q1 = ptsh[p][1], q2 = ptsh[p][2], q3 = ptsh[p][3];
#pragma unroll
        for (int r = 0; r < 8; ++r) {
            const int row = row0 + r;
            const float w0 = uWin[row*4+0], w1 = uWin[row*4+1];
            const float w2 = uWin[row*4+2], w3 = uWin[row*4+3];
            const float zz = ubin[row] + w0*q0 + w1*q1 + w2*q2 + w3*q3;
            const float a  = tanhf(zz);
            const float g  = 1.0f - a*a;
            const float m2 = -2.0f * a * g;
            act[row][c0+0] = a;
            act[row][c0+1] = g*w0; act[row][c0+2] = g*w1;
            act[row][c0+3] = g*w2; act[row][c0+4] = g*w3;
            act[row][c0+5] = m2*w0*w0; act[row][c0+6] = m2*w1*w1;
            act[row][c0+7] = m2*w2*w2; act[row][c0+8] = m2*w3*w3;
        }
    }
    __syncthreads();
    for (int l = 0; l < NHID; ++l) {
        const float* __restrict__ Wl = uWhid + l*WID*WID;
        float accv[8][9];
#pragma unroll
        for (int r = 0; r < 8; ++r) {
            accv[r][0] = ubhid[l*WID + row0 + r];
#pragma unroll
            for (int c = 1; c < 9; ++c) accv[r][c] = 0.0f;
        }
        for (int k0 = 0; k0 < WID; k0 += 4) {
            float4 wv[8];
#pragma unroll
            for (int r = 0; r < 8; ++r)
                wv[r] = *reinterpret_cast<const float4*>(&Wl[(row0+r)*WID + k0]);
            float hv[4][9];
#pragma unroll
            for (int kk = 0; kk < 4; ++kk)
#pragma unroll
                for (int c = 0; c < 9; ++c) hv[kk][c] = act[k0+kk][c0+c];
#pragma unroll
            for (int kk = 0; kk < 4; ++kk)
#pragma unroll
                for (int r = 0; r < 8; ++r) {
                    const float wk = reinterpret_cast<const float*>(&wv[r])[kk];
#pragma unroll
                    for (int c = 0; c < 9; ++c) accv[r][c] = fmaf(wk, hv[kk][c], accv[r][c]);
                }
        }
        __syncthreads();
#pragma unroll
        for (int r = 0; r < 8; ++r) {
            const int row = row0 + r;
            const float a = tanhf(accv[r][0]);
            const float g = 1.0f - a*a;
            act[row][c0+0] = a;
#pragma unroll
            for (int i = 0; i < 4; ++i) {
                const float zd  = accv[r][1+i];
                const float zdd = accv[r][5+i];
                act[row][c0+1+i] = g*zd;
                act[row][c0+5+i] = g*(zdd - 2.0f*a*zd*zd);
            }
        }
        __syncthreads();
    }
    if (tid < 64) {
        const int pp = tid >> 2, ii = tid & 3;
        float s = 0.0f;
        for (int k = 0; k < WID; ++k) s = fmaf(uWout[k], act[k][pp*9+5+ii], s);
        dsh[pp][ii] = s;
    }
    __syncthreads();
    if (tid < 16) {
        const float d0  = dsh[tid][0];
        const float lap = dsh[tid][1] + dsh[tid][2] + dsh[tid][3];
        out[base+tid] = d0 - c2g[base+tid]*lap;
    }
}

extern "C" void kernel_launch(void* const* d_in, const int* in_sizes, int n_in,
                              void* d_out, int out_size, void* d_ws, size_t ws_size,
                              hipStream_t stream)
{
    const float* gt    = (const float*)d_in[0];
    const float* gx    = (const float*)d_in[1];
    const float* gy    = (const float*)d_in[2];
    const float* gz    = (const float*)d_in[3];
    const float* uWin  = (const float*)d_in[4];
    const float* ubin  = (const float*)d_in[5];
    const float* uWhid = (const float*)d_in[6];
    const float* ubhid = (const float*)d_in[7];
    const float* uWout = (const float*)d_in[8];
    const float* pWin  = (const float*)d_in[10];
    const float* pbin  = (const float*)d_in[11];
    const float* pWhid = (const float*)d_in[12];
    const float* pbhid = (const float*)d_in[13];
    const float* pWout = (const float*)d_in[14];
    const float* pbout = (const float*)d_in[15];
    float* out = (float*)d_out;

    if (ws_size >= 327680) {
        unsigned short* whi = (unsigned short*)d_ws;
        unsigned short* wlo = whi + 81920;                       // 160 KB in
        pack_w<<<160, 64, 0, stream>>>(uWhid, whi, wlo);
        resid_mfma<<<NBLK, 256, 0, stream>>>(gt, gx, gy, gz,
                uWin, ubin, ubhid, uWout, whi, wlo,
                pWin, pbin, pWhid, pbhid, pWout, pbout, out);
    } else {
        float* c2 = (float*)d_ws;
        psi_kernel<<<N_PTS/64, 64, 0, stream>>>(gt, gx, gy, gz,
                pWin, pbin, pWhid, pbhid, pWout, pbout, c2);
        resid_f32<<<N_PTS/16, 256, 0, stream>>>(gt, gx, gy, gz,
                uWin, ubin, uWhid, ubhid, uWout, c2, out);
    }
}